// Round 14
// baseline (543.381 us; speedup 1.0000x reference)
//
#include <hip/hip_runtime.h>
#include <math.h>

#define N_NODES 100000
#define N_EDGES 300000
#define N_GRAPHS 2048
#define HIDDEN 256
#define NODE_IN 64
#define N_LAYERS 3
#define LN_EPS 1e-5f
#define GTILE 32
#define N_TILES (N_NODES / GTILE)   // 3125
#define BCAP 256                    // bucket capacity per tile (mean 96, ~16 sigma)
#define H2S 264                     // h2 bf16 row stride (256 + 8 pad)

typedef __attribute__((ext_vector_type(8))) short bf16x8;
typedef __attribute__((ext_vector_type(4))) float f32x4;

__device__ __forceinline__ float silu_f(float x) {
    return x / (1.f + expf(-x));
}

__device__ __forceinline__ short f2bf(float f) {
    union { float f; unsigned u; } v; v.f = f;
    unsigned r = v.u + 0x7fffu + ((v.u >> 16) & 1u);
    return (short)(r >> 16);
}

__device__ __forceinline__ float bf2f(short s) {
    union { unsigned u; float f; } v;
    v.u = ((unsigned)(unsigned short)s) << 16;
    return v.f;
}

// Wtin[n][k] = bf16(Win[k][n]), n in [0,256), k in [0,64)
__global__ __launch_bounds__(256) void prep_win(
        const float* __restrict__ Win, short* __restrict__ Wtin) {
    const int n = threadIdx.x;
    for (int k = 0; k < NODE_IN; ++k)
        Wtin[n * NODE_IN + k] = f2bf(Win[k * HIDDEN + n]);
}

// Wt[l][n][k] = bf16(W[l][k][n])  -- so B-fragments are contiguous in k
__global__ __launch_bounds__(256) void prep_wt(
        const float* __restrict__ W, short* __restrict__ Wt) {
    const int l = blockIdx.x >> 8;
    const int n = blockIdx.x & 255;
    const int k = threadIdx.x;
    Wt[((size_t)l * 256 + n) * 256 + k] = f2bf(W[((size_t)l * 256 + k) * 256 + n]);
}

// h(bf16) = silu(x @ W_in + b_in) via bf16 MFMA; 32 rows x 256 cols per block
__global__ __launch_bounds__(256) void input_proj_mfma(
        const float* __restrict__ x, const short* __restrict__ Wtin,
        const float* __restrict__ bin, short* __restrict__ h) {
    __shared__ __align__(16) char alds[GTILE * NODE_IN * 2];  // 4 KB bf16 A-tile
    const int t = threadIdx.x;
    const int b = blockIdx.x;

    const int srow = t >> 3;
    const int skg  = t & 7;
    const size_t xbase = ((size_t)b * GTILE + srow) * NODE_IN + skg * 8;
    float4 v0 = *reinterpret_cast<const float4*>(&x[xbase]);
    float4 v1 = *reinterpret_cast<const float4*>(&x[xbase + 4]);
    short a8[8];
    a8[0] = f2bf(v0.x); a8[1] = f2bf(v0.y); a8[2] = f2bf(v0.z); a8[3] = f2bf(v0.w);
    a8[4] = f2bf(v1.x); a8[5] = f2bf(v1.y); a8[6] = f2bf(v1.z); a8[7] = f2bf(v1.w);
    const int boff = srow * 128 + ((skg * 16) ^ ((srow & 7) << 4));
    *reinterpret_cast<bf16x8*>(alds + boff) = *reinterpret_cast<const bf16x8*>(a8);
    __syncthreads();

    const int w  = t >> 6;
    const int l  = t & 63;
    const int lr = l & 15;
    const int g  = l >> 4;
    f32x4 acc[2][4] = {};
    #pragma unroll
    for (int kt = 0; kt < 2; ++kt) {
        const int aoff = (kt * 64 + g * 16) ^ ((lr & 7) << 4);
        bf16x8 a0 = *reinterpret_cast<const bf16x8*>(alds + lr * 128 + aoff);
        bf16x8 a1 = *reinterpret_cast<const bf16x8*>(alds + (16 + lr) * 128 + aoff);
        #pragma unroll
        for (int ct = 0; ct < 4; ++ct) {
            bf16x8 bf = *reinterpret_cast<const bf16x8*>(
                Wtin + (w * 64 + ct * 16 + lr) * NODE_IN + kt * 32 + g * 8);
            acc[0][ct] = __builtin_amdgcn_mfma_f32_16x16x32_bf16(a0, bf, acc[0][ct], 0, 0, 0);
            acc[1][ct] = __builtin_amdgcn_mfma_f32_16x16x32_bf16(a1, bf, acc[1][ct], 0, 0, 0);
        }
    }

    #pragma unroll
    for (int ct = 0; ct < 4; ++ct) {
        const int col = w * 64 + ct * 16 + lr;
        const float bs = bin[col];
        #pragma unroll
        for (int rt = 0; rt < 2; ++rt) {
            #pragma unroll
            for (int j = 0; j < 4; ++j) {
                const int row = rt * 16 + g * 4 + j;
                h[((size_t)b * GTILE + row) * HIDDEN + col] = f2bf(silu_f(acc[rt][ct][j] + bs));
            }
        }
    }
}

// ---- CSR-by-destination-row bucket build (3 passes, one-time) ----

__global__ __launch_bounds__(256) void count_rows(
        const int* __restrict__ dst, int* __restrict__ cnt32) {
    const int e = blockIdx.x * 256 + threadIdx.x;
    if (e >= N_EDGES) return;
    atomicAdd(&cnt32[dst[e]], 1);
}

__global__ __launch_bounds__(64) void scan_rows(
        int* __restrict__ cnt32, int* __restrict__ rowoff) {
    const int tile = blockIdx.x;
    const int lane = threadIdx.x;
    if (lane < 32) {
        const int v = cnt32[tile * 32 + lane];
        int incl = v;
        #pragma unroll
        for (int d = 1; d < 32; d <<= 1) {
            const int u = __shfl_up(incl, d);
            if (lane >= d) incl += u;
        }
        const int excl = incl - v;
        rowoff[tile * 33 + lane] = excl;
        cnt32[tile * 32 + lane] = excl;       // becomes the scatter cursor
        if (lane == 31) rowoff[tile * 33 + 32] = incl;
    }
}

__global__ __launch_bounds__(256) void fill_bucket(
        const int* __restrict__ src, const int* __restrict__ dst,
        int* __restrict__ cursor, int* __restrict__ bucket) {
    const int e = blockIdx.x * 256 + threadIdx.x;
    if (e >= N_EDGES) return;
    const int d = dst[e];
    const int pos = atomicAdd(&cursor[d], 1);    // tile-relative offset
    if (pos < BCAP) bucket[(d >> 5) * BCAP + pos] = src[e];
}

// Fused per-layer kernel (h stored bf16, h2 staged bf16 in LDS):
//   agg = h + sum_{edges into row} relu(h[src])   (per-row CSR span, 2-deep ILP)
//   out = silu(LN(agg @ W + b) * gamma + beta) + h   via bf16 MFMA
// launch_bounds(256,4): 128-reg cap -- roomy, so the allocator keeps macc[32]
// in registers (no scratch). Body lands ~96-104 regs; if <=102 the HW gives
// 5 waves/EU naturally. (256,5) forced a 44-reg allocation + scratch spill.
__global__ __launch_bounds__(256, 4) void layer_fused(
        const short* __restrict__ h, const int* __restrict__ rowoff,
        const int* __restrict__ bucket,
        const short* __restrict__ Wt, const float* __restrict__ bias,
        const float* __restrict__ gamma, const float* __restrict__ beta,
        short* __restrict__ out) {
    // union: A-tile bf16 [32][256] swizzled (16 KB) -> h2 bf16 [32][264] (16.9 KB)
    __shared__ __align__(16) char smem[GTILE * H2S * 2];
    __shared__ float mu_s[GTILE], rs_s[GTILE];
    __shared__ int ebuf[BCAP];

    const int t = threadIdx.x;
    const int b = blockIdx.x;
    const size_t base = (size_t)b * GTILE * HIDDEN;

    const int srow = t >> 3;        // row within tile (8-lane group)
    const int scg  = t & 7;         // col group of 32

    const int total = min(rowoff[b * 33 + 32], BCAP);
    const int off0  = min(rowoff[b * 33 + srow], BCAP);
    const int off1  = min(rowoff[b * 33 + srow + 1], BCAP);
    for (int i = t; i < total; i += 256) ebuf[i] = bucket[b * BCAP + i];

    // ---- init: macc = h(self) ----
    const size_t rowbase = base + (size_t)srow * HIDDEN + scg * 32;
    float macc[32];
    #pragma unroll
    for (int i = 0; i < 4; ++i) {
        bf16x8 hv = *reinterpret_cast<const bf16x8*>(&h[rowbase + i * 8]);
        #pragma unroll
        for (int k = 0; k < 8; ++k) macc[i * 8 + k] = bf2f(hv[k]);
    }
    __syncthreads();   // ebuf ready

    // ---- gather: each 8-lane group walks its row's span, 2 entries deep ----
    {
        int i = off0;
        while (i + 1 < off1) {
            const int s0 = ebuf[i];
            const int s1 = ebuf[i + 1];
            const short* p0 = &h[(size_t)s0 * HIDDEN + scg * 32];
            const short* p1 = &h[(size_t)s1 * HIDDEN + scg * 32];
            bf16x8 u0[4], u1[4];
            #pragma unroll
            for (int j = 0; j < 4; ++j) u0[j] = *reinterpret_cast<const bf16x8*>(&p0[j * 8]);
            #pragma unroll
            for (int j = 0; j < 4; ++j) u1[j] = *reinterpret_cast<const bf16x8*>(&p1[j * 8]);
            #pragma unroll
            for (int j = 0; j < 4; ++j) {
                #pragma unroll
                for (int k = 0; k < 8; ++k) {
                    macc[j * 8 + k] += fmaxf(bf2f(u0[j][k]), 0.f) + fmaxf(bf2f(u1[j][k]), 0.f);
                }
            }
            i += 2;
        }
        if (i < off1) {
            const int s0 = ebuf[i];
            const short* p0 = &h[(size_t)s0 * HIDDEN + scg * 32];
            bf16x8 u0[4];
            #pragma unroll
            for (int j = 0; j < 4; ++j) u0[j] = *reinterpret_cast<const bf16x8*>(&p0[j * 8]);
            #pragma unroll
            for (int j = 0; j < 4; ++j) {
                #pragma unroll
                for (int k = 0; k < 8; ++k)
                    macc[j * 8 + k] += fmaxf(bf2f(u0[j][k]), 0.f);
            }
        }
    }

    // ---- write bf16 A-tile (XOR-swizzled rows of 512B) ----
    #pragma unroll
    for (int j = 0; j < 4; ++j) {
        short abf[8];
        #pragma unroll
        for (int k = 0; k < 8; ++k) abf[k] = f2bf(macc[j * 8 + k]);
        const int boff = srow * 512 + ((scg * 64 + j * 16) ^ ((srow & 7) << 4));
        *reinterpret_cast<bf16x8*>(smem + boff) =
            *reinterpret_cast<const bf16x8*>(abf);
    }
    __syncthreads();

    // ---- MFMA: 2 row-tiles x 4 col-tiles per wave, K = 8 x 32 ----
    const int w  = t >> 6;
    const int l  = t & 63;
    const int lr = l & 15;
    const int g  = l >> 4;
    f32x4 acc[2][4] = {};
    const short* wbase = Wt + (size_t)(w * 64 + lr) * 256 + g * 8;
    #pragma unroll
    for (int kt = 0; kt < 8; ++kt) {
        const int aoff = ((kt * 64 + g * 16) ^ ((lr & 7) << 4));
        bf16x8 a0 = *reinterpret_cast<const bf16x8*>(smem + lr * 512 + aoff);
        bf16x8 a1 = *reinterpret_cast<const bf16x8*>(smem + (16 + lr) * 512 + aoff);
        #pragma unroll
        for (int ct = 0; ct < 4; ++ct) {
            bf16x8 bf = *reinterpret_cast<const bf16x8*>(wbase + (size_t)ct * 16 * 256 + kt * 32);
            acc[0][ct] = __builtin_amdgcn_mfma_f32_16x16x32_bf16(a0, bf, acc[0][ct], 0, 0, 0);
            acc[1][ct] = __builtin_amdgcn_mfma_f32_16x16x32_bf16(a1, bf, acc[1][ct], 0, 0, 0);
        }
    }
    __syncthreads();   // done reading A-tile; smem becomes h2 bf16 [32][264]

    // ---- write h2 = bf16(acc + bias) ----
    short* h2s = reinterpret_cast<short*>(smem);
    #pragma unroll
    for (int ct = 0; ct < 4; ++ct) {
        const int col = w * 64 + ct * 16 + lr;
        const float bs = bias[col];
        #pragma unroll
        for (int rt = 0; rt < 2; ++rt) {
            #pragma unroll
            for (int j = 0; j < 4; ++j) {
                const int row = rt * 16 + g * 4 + j;
                h2s[row * H2S + col] = f2bf(acc[rt][ct][j] + bs);
            }
        }
    }
    __syncthreads();

    // ---- LN stats: single pass (sum + sumsq), 8 threads per row ----
    {
        const int n = t >> 3, jj = t & 7;
        float s = 0.f, q = 0.f;
        #pragma unroll
        for (int ii = 0; ii < HIDDEN / 8; ++ii) {
            const float xv = bf2f(h2s[n * H2S + jj + 8 * ii]);
            s += xv; q += xv * xv;
        }
        s += __shfl_xor(s, 1); s += __shfl_xor(s, 2); s += __shfl_xor(s, 4);
        q += __shfl_xor(q, 1); q += __shfl_xor(q, 2); q += __shfl_xor(q, 4);
        if (jj == 0) {
            const float mu = s * (1.f / HIDDEN);
            const float var = fmaxf(q * (1.f / HIDDEN) - mu * mu, 0.f);
            mu_s[n] = mu;
            rs_s[n] = rsqrtf(var + LN_EPS);
        }
    }
    __syncthreads();

    // ---- epilogue: out = bf16(silu(LN) + h); h re-read (L2-hot) ----
    const float mu = mu_s[srow], rs = rs_s[srow];
    #pragma unroll
    for (int i = 0; i < 4; ++i) {
        const int c0 = scg * 32 + i * 8;
        const float4 g0 = *reinterpret_cast<const float4*>(&gamma[c0]);
        const float4 g1 = *reinterpret_cast<const float4*>(&gamma[c0 + 4]);
        const float4 b0 = *reinterpret_cast<const float4*>(&beta[c0]);
        const float4 b1 = *reinterpret_cast<const float4*>(&beta[c0 + 4]);
        bf16x8 hv = *reinterpret_cast<const bf16x8*>(&h2s[srow * H2S + c0]);
        bf16x8 hr = *reinterpret_cast<const bf16x8*>(&h[rowbase + i * 8]);
        short o8[8];
        o8[0] = f2bf(silu_f((bf2f(hv[0]) - mu) * rs * g0.x + b0.x) + bf2f(hr[0]));
        o8[1] = f2bf(silu_f((bf2f(hv[1]) - mu) * rs * g0.y + b0.y) + bf2f(hr[1]));
        o8[2] = f2bf(silu_f((bf2f(hv[2]) - mu) * rs * g0.z + b0.z) + bf2f(hr[2]));
        o8[3] = f2bf(silu_f((bf2f(hv[3]) - mu) * rs * g0.w + b0.w) + bf2f(hr[3]));
        o8[4] = f2bf(silu_f((bf2f(hv[4]) - mu) * rs * g1.x + b1.x) + bf2f(hr[4]));
        o8[5] = f2bf(silu_f((bf2f(hv[5]) - mu) * rs * g1.y + b1.y) + bf2f(hr[5]));
        o8[6] = f2bf(silu_f((bf2f(hv[6]) - mu) * rs * g1.z + b1.z) + bf2f(hr[6]));
        o8[7] = f2bf(silu_f((bf2f(hv[7]) - mu) * rs * g1.w + b1.w) + bf2f(hr[7]));
        *reinterpret_cast<bf16x8*>(&out[rowbase + i * 8]) =
            *reinterpret_cast<const bf16x8*>(o8);
    }
}

// global mean pool over sorted batch_ids; one block per graph; h is bf16
__global__ __launch_bounds__(256) void pool_mean(
        const short* __restrict__ h, const int* __restrict__ bid,
        float* __restrict__ out) {
    const int g = blockIdx.x, t = threadIdx.x;
    int lo = 0, hi = N_NODES;
    while (lo < hi) { int mid = (lo + hi) >> 1; if (bid[mid] < g) lo = mid + 1; else hi = mid; }
    const int start = lo;
    hi = N_NODES;
    while (lo < hi) { int mid = (lo + hi) >> 1; if (bid[mid] < g + 1) lo = mid + 1; else hi = mid; }
    const int end = lo;
    float s = 0.f;
    int n = start;
    for (; n + 4 <= end; n += 4) {
        const float v0 = bf2f(h[(size_t)(n + 0) * HIDDEN + t]);
        const float v1 = bf2f(h[(size_t)(n + 1) * HIDDEN + t]);
        const float v2 = bf2f(h[(size_t)(n + 2) * HIDDEN + t]);
        const float v3 = bf2f(h[(size_t)(n + 3) * HIDDEN + t]);
        s += (v0 + v1) + (v2 + v3);
    }
    for (; n < end; ++n) s += bf2f(h[(size_t)n * HIDDEN + t]);
    const float cnt = (float)(end - start);
    out[(size_t)g * HIDDEN + t] = s / fmaxf(cnt, 1.f);
}

extern "C" void kernel_launch(void* const* d_in, const int* in_sizes, int n_in,
                              void* d_out, int out_size, void* d_ws, size_t ws_size,
                              hipStream_t stream) {
    const float* x     = (const float*)d_in[0];
    const int*   ei    = (const int*)d_in[1];
    const int*   bid   = (const int*)d_in[2];
    const float* Win   = (const float*)d_in[3];
    const float* bin   = (const float*)d_in[4];
    const float* W     = (const float*)d_in[5];
    const float* b     = (const float*)d_in[6];
    const float* gamma = (const float*)d_in[7];
    const float* beta  = (const float*)d_in[8];
    float* out = (float*)d_out;

    const size_t hElems = (size_t)N_NODES * HIDDEN;
    short* A     = (short*)d_ws;                        // bf16 h ping
    short* B     = A + hElems;                          // bf16 h pong
    short* Wt    = B + hElems;
    short* Wtin  = Wt + (size_t)N_LAYERS * HIDDEN * HIDDEN;
    int* cnt32   = (int*)(Wtin + HIDDEN * NODE_IN);     // per-node count -> cursor
    int* rowoff  = cnt32 + N_NODES;                     // 3125 * 33
    int* bucket  = rowoff + N_TILES * 33;               // 3125 * 256

    const int* src = ei;
    const int* dst = ei + N_EDGES;

    hipMemsetAsync(cnt32, 0, N_NODES * sizeof(int), stream);
    count_rows<<<(N_EDGES + 255) / 256, 256, 0, stream>>>(dst, cnt32);
    scan_rows<<<N_TILES, 64, 0, stream>>>(cnt32, rowoff);
    fill_bucket<<<(N_EDGES + 255) / 256, 256, 0, stream>>>(src, dst, cnt32, bucket);

    prep_win<<<1, 256, 0, stream>>>(Win, Wtin);
    prep_wt<<<N_LAYERS * 256, 256, 0, stream>>>(W, Wt);
    input_proj_mfma<<<N_TILES, 256, 0, stream>>>(x, Wtin, bin, A);

    short* cur = A;
    short* alt = B;
    for (int l = 0; l < N_LAYERS; ++l) {
        layer_fused<<<N_TILES, 256, 0, stream>>>(
            cur, rowoff, bucket, Wt + (size_t)l * HIDDEN * HIDDEN,
            b + (size_t)l * HIDDEN, gamma + (size_t)l * HIDDEN,
            beta + (size_t)l * HIDDEN, alt);
        short* tmp = cur; cur = alt; alt = tmp;
    }
    pool_mean<<<N_GRAPHS, 256, 0, stream>>>(cur, bid, out);
}

// Round 15
// 497.965 us; speedup vs baseline: 1.0912x; 1.0912x over previous
//
#include <hip/hip_runtime.h>
#include <math.h>

#define N_NODES 100000
#define N_EDGES 300000
#define N_GRAPHS 2048
#define HIDDEN 256
#define NODE_IN 64
#define N_LAYERS 3
#define LN_EPS 1e-5f
#define GTILE 32
#define N_TILES (N_NODES / GTILE)   // 3125
#define BCAP 256                    // bucket capacity per tile (mean 96, ~16 sigma)
#define H2S 264                     // h2 bf16 row stride (256 + 8 pad)

typedef __attribute__((ext_vector_type(8))) short bf16x8;
typedef __attribute__((ext_vector_type(4))) float f32x4;

__device__ __forceinline__ float silu_f(float x) {
    return x / (1.f + expf(-x));
}

__device__ __forceinline__ short f2bf(float f) {
    union { float f; unsigned u; } v; v.f = f;
    unsigned r = v.u + 0x7fffu + ((v.u >> 16) & 1u);
    return (short)(r >> 16);
}

__device__ __forceinline__ float bf2f(short s) {
    union { unsigned u; float f; } v;
    v.u = ((unsigned)(unsigned short)s) << 16;
    return v.f;
}

// Wtin[n][k] = bf16(Win[k][n]), n in [0,256), k in [0,64)
__global__ __launch_bounds__(256) void prep_win(
        const float* __restrict__ Win, short* __restrict__ Wtin) {
    const int n = threadIdx.x;
    for (int k = 0; k < NODE_IN; ++k)
        Wtin[n * NODE_IN + k] = f2bf(Win[k * HIDDEN + n]);
}

// Wt[l][n][k] = bf16(W[l][k][n])  -- so B-fragments are contiguous in k
__global__ __launch_bounds__(256) void prep_wt(
        const float* __restrict__ W, short* __restrict__ Wt) {
    const int l = blockIdx.x >> 8;
    const int n = blockIdx.x & 255;
    const int k = threadIdx.x;
    Wt[((size_t)l * 256 + n) * 256 + k] = f2bf(W[((size_t)l * 256 + k) * 256 + n]);
}

// h(bf16) = silu(x @ W_in + b_in) via bf16 MFMA; 32 rows x 256 cols per block
__global__ __launch_bounds__(256) void input_proj_mfma(
        const float* __restrict__ x, const short* __restrict__ Wtin,
        const float* __restrict__ bin, short* __restrict__ h) {
    __shared__ __align__(16) char alds[GTILE * NODE_IN * 2];  // 4 KB bf16 A-tile
    const int t = threadIdx.x;
    const int b = blockIdx.x;

    const int srow = t >> 3;
    const int skg  = t & 7;
    const size_t xbase = ((size_t)b * GTILE + srow) * NODE_IN + skg * 8;
    float4 v0 = *reinterpret_cast<const float4*>(&x[xbase]);
    float4 v1 = *reinterpret_cast<const float4*>(&x[xbase + 4]);
    short a8[8];
    a8[0] = f2bf(v0.x); a8[1] = f2bf(v0.y); a8[2] = f2bf(v0.z); a8[3] = f2bf(v0.w);
    a8[4] = f2bf(v1.x); a8[5] = f2bf(v1.y); a8[6] = f2bf(v1.z); a8[7] = f2bf(v1.w);
    const int boff = srow * 128 + ((skg * 16) ^ ((srow & 7) << 4));
    *reinterpret_cast<bf16x8*>(alds + boff) = *reinterpret_cast<const bf16x8*>(a8);
    __syncthreads();

    const int w  = t >> 6;
    const int l  = t & 63;
    const int lr = l & 15;
    const int g  = l >> 4;
    f32x4 acc[2][4] = {};
    #pragma unroll
    for (int kt = 0; kt < 2; ++kt) {
        const int aoff = (kt * 64 + g * 16) ^ ((lr & 7) << 4);
        bf16x8 a0 = *reinterpret_cast<const bf16x8*>(alds + lr * 128 + aoff);
        bf16x8 a1 = *reinterpret_cast<const bf16x8*>(alds + (16 + lr) * 128 + aoff);
        #pragma unroll
        for (int ct = 0; ct < 4; ++ct) {
            bf16x8 bf = *reinterpret_cast<const bf16x8*>(
                Wtin + (w * 64 + ct * 16 + lr) * NODE_IN + kt * 32 + g * 8);
            acc[0][ct] = __builtin_amdgcn_mfma_f32_16x16x32_bf16(a0, bf, acc[0][ct], 0, 0, 0);
            acc[1][ct] = __builtin_amdgcn_mfma_f32_16x16x32_bf16(a1, bf, acc[1][ct], 0, 0, 0);
        }
    }

    #pragma unroll
    for (int ct = 0; ct < 4; ++ct) {
        const int col = w * 64 + ct * 16 + lr;
        const float bs = bin[col];
        #pragma unroll
        for (int rt = 0; rt < 2; ++rt) {
            #pragma unroll
            for (int j = 0; j < 4; ++j) {
                const int row = rt * 16 + g * 4 + j;
                h[((size_t)b * GTILE + row) * HIDDEN + col] = f2bf(silu_f(acc[rt][ct][j] + bs));
            }
        }
    }
}

// ---- CSR-by-destination-row bucket build (3 passes, one-time) ----

__global__ __launch_bounds__(256) void count_rows(
        const int* __restrict__ dst, int* __restrict__ cnt32) {
    const int e = blockIdx.x * 256 + threadIdx.x;
    if (e >= N_EDGES) return;
    atomicAdd(&cnt32[dst[e]], 1);
}

__global__ __launch_bounds__(64) void scan_rows(
        int* __restrict__ cnt32, int* __restrict__ rowoff) {
    const int tile = blockIdx.x;
    const int lane = threadIdx.x;
    if (lane < 32) {
        const int v = cnt32[tile * 32 + lane];
        int incl = v;
        #pragma unroll
        for (int d = 1; d < 32; d <<= 1) {
            const int u = __shfl_up(incl, d);
            if (lane >= d) incl += u;
        }
        const int excl = incl - v;
        rowoff[tile * 33 + lane] = excl;
        cnt32[tile * 32 + lane] = excl;       // becomes the scatter cursor
        if (lane == 31) rowoff[tile * 33 + 32] = incl;
    }
}

__global__ __launch_bounds__(256) void fill_bucket(
        const int* __restrict__ src, const int* __restrict__ dst,
        int* __restrict__ cursor, int* __restrict__ bucket) {
    const int e = blockIdx.x * 256 + threadIdx.x;
    if (e >= N_EDGES) return;
    const int d = dst[e];
    const int pos = atomicAdd(&cursor[d], 1);    // tile-relative offset
    if (pos < BCAP) bucket[(d >> 5) * BCAP + pos] = src[e];
}

// Fused per-layer kernel (h stored bf16, h2 staged bf16 in LDS):
//   agg = h + sum_{edges into row} relu(h[src])
//   out = silu(LN(agg @ W + b) * gamma + beta) + h   via bf16 MFMA
// Gather is 2 passes x 16 cols per 8-lane group: halves per-thread live state
// (macc[16] + 16 staging regs) so the natural allocation stays ~64-72 VGPR
// with NO spill and LDS (18.4 KB) permits up to 8 blocks/CU.
__global__ __launch_bounds__(256) void layer_fused(
        const short* __restrict__ h, const int* __restrict__ rowoff,
        const int* __restrict__ bucket,
        const short* __restrict__ Wt, const float* __restrict__ bias,
        const float* __restrict__ gamma, const float* __restrict__ beta,
        short* __restrict__ out) {
    // union: A-tile bf16 [32][256] swizzled (16 KB) -> h2 bf16 [32][264] (16.9 KB)
    __shared__ __align__(16) char smem[GTILE * H2S * 2];
    __shared__ float mu_s[GTILE], rs_s[GTILE];
    __shared__ int ebuf[BCAP];

    const int t = threadIdx.x;
    const int b = blockIdx.x;
    const size_t base = (size_t)b * GTILE * HIDDEN;

    const int srow = t >> 3;        // row within tile (8-lane group)
    const int scg  = t & 7;         // 16-col sub-slot within each 128-col half

    const int total = min(rowoff[b * 33 + 32], BCAP);
    const int off0  = min(rowoff[b * 33 + srow], BCAP);
    const int off1  = min(rowoff[b * 33 + srow + 1], BCAP);
    for (int i = t; i < total; i += 256) ebuf[i] = bucket[b * BCAP + i];
    __syncthreads();   // ebuf ready

    const int swz = (srow & 7) << 4;

    // ---- gather: 2 passes of 16 cols; macc[16] + 2-deep staging per pass ----
    #pragma unroll 1
    for (int p = 0; p < 2; ++p) {
        const int cb = p * 128 + scg * 16;     // col base for this pass
        const size_t selfoff = base + (size_t)srow * HIDDEN + cb;

        float macc[16];
        {
            bf16x8 h0 = *reinterpret_cast<const bf16x8*>(&h[selfoff]);
            bf16x8 h1 = *reinterpret_cast<const bf16x8*>(&h[selfoff + 8]);
            #pragma unroll
            for (int k = 0; k < 8; ++k) { macc[k] = bf2f(h0[k]); macc[8 + k] = bf2f(h1[k]); }
        }

        int i = off0;
        while (i + 1 < off1) {
            const int s0 = ebuf[i];
            const int s1 = ebuf[i + 1];
            const short* p0 = &h[(size_t)s0 * HIDDEN + cb];
            const short* p1 = &h[(size_t)s1 * HIDDEN + cb];
            bf16x8 u0a = *reinterpret_cast<const bf16x8*>(p0);
            bf16x8 u0b = *reinterpret_cast<const bf16x8*>(p0 + 8);
            bf16x8 u1a = *reinterpret_cast<const bf16x8*>(p1);
            bf16x8 u1b = *reinterpret_cast<const bf16x8*>(p1 + 8);
            #pragma unroll
            for (int k = 0; k < 8; ++k) {
                macc[k]     += fmaxf(bf2f(u0a[k]), 0.f) + fmaxf(bf2f(u1a[k]), 0.f);
                macc[8 + k] += fmaxf(bf2f(u0b[k]), 0.f) + fmaxf(bf2f(u1b[k]), 0.f);
            }
            i += 2;
        }
        if (i < off1) {
            const int s0 = ebuf[i];
            const short* p0 = &h[(size_t)s0 * HIDDEN + cb];
            bf16x8 u0a = *reinterpret_cast<const bf16x8*>(p0);
            bf16x8 u0b = *reinterpret_cast<const bf16x8*>(p0 + 8);
            #pragma unroll
            for (int k = 0; k < 8; ++k) {
                macc[k]     += fmaxf(bf2f(u0a[k]), 0.f);
                macc[8 + k] += fmaxf(bf2f(u0b[k]), 0.f);
            }
        }

        // write 2 swizzled 16B A-tile slots (same content mapping as before)
        short abf[8];
        #pragma unroll
        for (int k = 0; k < 8; ++k) abf[k] = f2bf(macc[k]);
        *reinterpret_cast<bf16x8*>(smem + srow * 512 + ((p * 256 + scg * 32) ^ swz)) =
            *reinterpret_cast<const bf16x8*>(abf);
        #pragma unroll
        for (int k = 0; k < 8; ++k) abf[k] = f2bf(macc[8 + k]);
        *reinterpret_cast<bf16x8*>(smem + srow * 512 + ((p * 256 + scg * 32 + 16) ^ swz)) =
            *reinterpret_cast<const bf16x8*>(abf);
    }
    __syncthreads();

    // ---- MFMA: 2 row-tiles x 4 col-tiles per wave, K = 8 x 32 ----
    const int w  = t >> 6;
    const int l  = t & 63;
    const int lr = l & 15;
    const int g  = l >> 4;
    f32x4 acc[2][4] = {};
    const short* wbase = Wt + (size_t)(w * 64 + lr) * 256 + g * 8;
    #pragma unroll
    for (int kt = 0; kt < 8; ++kt) {
        const int aoff = ((kt * 64 + g * 16) ^ ((lr & 7) << 4));
        bf16x8 a0 = *reinterpret_cast<const bf16x8*>(smem + lr * 512 + aoff);
        bf16x8 a1 = *reinterpret_cast<const bf16x8*>(smem + (16 + lr) * 512 + aoff);
        #pragma unroll
        for (int ct = 0; ct < 4; ++ct) {
            bf16x8 bf = *reinterpret_cast<const bf16x8*>(wbase + (size_t)ct * 16 * 256 + kt * 32);
            acc[0][ct] = __builtin_amdgcn_mfma_f32_16x16x32_bf16(a0, bf, acc[0][ct], 0, 0, 0);
            acc[1][ct] = __builtin_amdgcn_mfma_f32_16x16x32_bf16(a1, bf, acc[1][ct], 0, 0, 0);
        }
    }
    __syncthreads();   // done reading A-tile; smem becomes h2 bf16 [32][264]

    // ---- write h2 = bf16(acc + bias) ----
    short* h2s = reinterpret_cast<short*>(smem);
    #pragma unroll
    for (int ct = 0; ct < 4; ++ct) {
        const int col = w * 64 + ct * 16 + lr;
        const float bs = bias[col];
        #pragma unroll
        for (int rt = 0; rt < 2; ++rt) {
            #pragma unroll
            for (int j = 0; j < 4; ++j) {
                const int row = rt * 16 + g * 4 + j;
                h2s[row * H2S + col] = f2bf(acc[rt][ct][j] + bs);
            }
        }
    }
    __syncthreads();

    // ---- LN stats: single pass (sum + sumsq), 8 threads per row ----
    {
        const int n = t >> 3, jj = t & 7;
        float s = 0.f, q = 0.f;
        #pragma unroll
        for (int ii = 0; ii < HIDDEN / 8; ++ii) {
            const float xv = bf2f(h2s[n * H2S + jj + 8 * ii]);
            s += xv; q += xv * xv;
        }
        s += __shfl_xor(s, 1); s += __shfl_xor(s, 2); s += __shfl_xor(s, 4);
        q += __shfl_xor(q, 1); q += __shfl_xor(q, 2); q += __shfl_xor(q, 4);
        if (jj == 0) {
            const float mu = s * (1.f / HIDDEN);
            const float var = fmaxf(q * (1.f / HIDDEN) - mu * mu, 0.f);
            mu_s[n] = mu;
            rs_s[n] = rsqrtf(var + LN_EPS);
        }
    }
    __syncthreads();

    // ---- epilogue: out = bf16(silu(LN) + h); h re-read (L2-hot) ----
    const float mu = mu_s[srow], rs = rs_s[srow];
    const size_t rowbase = base + (size_t)srow * HIDDEN + scg * 32;
    #pragma unroll
    for (int i = 0; i < 4; ++i) {
        const int c0 = scg * 32 + i * 8;
        const float4 g0 = *reinterpret_cast<const float4*>(&gamma[c0]);
        const float4 g1 = *reinterpret_cast<const float4*>(&gamma[c0 + 4]);
        const float4 b0 = *reinterpret_cast<const float4*>(&beta[c0]);
        const float4 b1 = *reinterpret_cast<const float4*>(&beta[c0 + 4]);
        bf16x8 hv = *reinterpret_cast<const bf16x8*>(&h2s[srow * H2S + c0]);
        bf16x8 hr = *reinterpret_cast<const bf16x8*>(&h[rowbase + i * 8]);
        short o8[8];
        o8[0] = f2bf(silu_f((bf2f(hv[0]) - mu) * rs * g0.x + b0.x) + bf2f(hr[0]));
        o8[1] = f2bf(silu_f((bf2f(hv[1]) - mu) * rs * g0.y + b0.y) + bf2f(hr[1]));
        o8[2] = f2bf(silu_f((bf2f(hv[2]) - mu) * rs * g0.z + b0.z) + bf2f(hr[2]));
        o8[3] = f2bf(silu_f((bf2f(hv[3]) - mu) * rs * g0.w + b0.w) + bf2f(hr[3]));
        o8[4] = f2bf(silu_f((bf2f(hv[4]) - mu) * rs * g1.x + b1.x) + bf2f(hr[4]));
        o8[5] = f2bf(silu_f((bf2f(hv[5]) - mu) * rs * g1.y + b1.y) + bf2f(hr[5]));
        o8[6] = f2bf(silu_f((bf2f(hv[6]) - mu) * rs * g1.z + b1.z) + bf2f(hr[6]));
        o8[7] = f2bf(silu_f((bf2f(hv[7]) - mu) * rs * g1.w + b1.w) + bf2f(hr[7]));
        *reinterpret_cast<bf16x8*>(&out[rowbase + i * 8]) =
            *reinterpret_cast<const bf16x8*>(o8);
    }
}

// global mean pool over sorted batch_ids; one block per graph; h is bf16
__global__ __launch_bounds__(256) void pool_mean(
        const short* __restrict__ h, const int* __restrict__ bid,
        float* __restrict__ out) {
    const int g = blockIdx.x, t = threadIdx.x;
    int lo = 0, hi = N_NODES;
    while (lo < hi) { int mid = (lo + hi) >> 1; if (bid[mid] < g) lo = mid + 1; else hi = mid; }
    const int start = lo;
    hi = N_NODES;
    while (lo < hi) { int mid = (lo + hi) >> 1; if (bid[mid] < g + 1) lo = mid + 1; else hi = mid; }
    const int end = lo;
    float s = 0.f;
    int n = start;
    for (; n + 4 <= end; n += 4) {
        const float v0 = bf2f(h[(size_t)(n + 0) * HIDDEN + t]);
        const float v1 = bf2f(h[(size_t)(n + 1) * HIDDEN + t]);
        const float v2 = bf2f(h[(size_t)(n + 2) * HIDDEN + t]);
        const float v3 = bf2f(h[(size_t)(n + 3) * HIDDEN + t]);
        s += (v0 + v1) + (v2 + v3);
    }
    for (; n < end; ++n) s += bf2f(h[(size_t)n * HIDDEN + t]);
    const float cnt = (float)(end - start);
    out[(size_t)g * HIDDEN + t] = s / fmaxf(cnt, 1.f);
}

extern "C" void kernel_launch(void* const* d_in, const int* in_sizes, int n_in,
                              void* d_out, int out_size, void* d_ws, size_t ws_size,
                              hipStream_t stream) {
    const float* x     = (const float*)d_in[0];
    const int*   ei    = (const int*)d_in[1];
    const int*   bid   = (const int*)d_in[2];
    const float* Win   = (const float*)d_in[3];
    const float* bin   = (const float*)d_in[4];
    const float* W     = (const float*)d_in[5];
    const float* b     = (const float*)d_in[6];
    const float* gamma = (const float*)d_in[7];
    const float* beta  = (const float*)d_in[8];
    float* out = (float*)d_out;

    const size_t hElems = (size_t)N_NODES * HIDDEN;
    short* A     = (short*)d_ws;                        // bf16 h ping
    short* B     = A + hElems;                          // bf16 h pong
    short* Wt    = B + hElems;
    short* Wtin  = Wt + (size_t)N_LAYERS * HIDDEN * HIDDEN;
    int* cnt32   = (int*)(Wtin + HIDDEN * NODE_IN);     // per-node count -> cursor
    int* rowoff  = cnt32 + N_NODES;                     // 3125 * 33
    int* bucket  = rowoff + N_TILES * 33;               // 3125 * 256

    const int* src = ei;
    const int* dst = ei + N_EDGES;

    hipMemsetAsync(cnt32, 0, N_NODES * sizeof(int), stream);
    count_rows<<<(N_EDGES + 255) / 256, 256, 0, stream>>>(dst, cnt32);
    scan_rows<<<N_TILES, 64, 0, stream>>>(cnt32, rowoff);
    fill_bucket<<<(N_EDGES + 255) / 256, 256, 0, stream>>>(src, dst, cnt32, bucket);

    prep_win<<<1, 256, 0, stream>>>(Win, Wtin);
    prep_wt<<<N_LAYERS * 256, 256, 0, stream>>>(W, Wt);
    input_proj_mfma<<<N_TILES, 256, 0, stream>>>(x, Wtin, bin, A);

    short* cur = A;
    short* alt = B;
    for (int l = 0; l < N_LAYERS; ++l) {
        layer_fused<<<N_TILES, 256, 0, stream>>>(
            cur, rowoff, bucket, Wt + (size_t)l * HIDDEN * HIDDEN,
            b + (size_t)l * HIDDEN, gamma + (size_t)l * HIDDEN,
            beta + (size_t)l * HIDDEN, alt);
        short* tmp = cur; cur = alt; alt = tmp;
    }
    pool_mean<<<N_GRAPHS, 256, 0, stream>>>(cur, bid, out);
}